// Round 5
// baseline (127.357 us; speedup 1.0000x reference)
//
#include <hip/hip_runtime.h>
#include <math.h>

#define T_DIM 4096
#define F_DIM 256
#define NROWS 4096          // B*C*F = 16*1*256
#define CHUNK 16            // elements per thread; 256 threads * 16 = 4096 = T
#define LOG2E 1.4426950408889634f

typedef float v2f __attribute__((ext_vector_type(2)));

__device__ __forceinline__ float fexp2(float v) { return __builtin_amdgcn_exp2f(v); }
__device__ __forceinline__ float flog2(float v) { return __builtin_amdgcn_logf(v); }
__device__ __forceinline__ float fexp(float v)  { return fexp2(v * LOG2E); }

__host__ __device__ constexpr float cpow(float b, int e) {
    float r = 1.0f;
    for (int i = 0; i < e; ++i) r *= b;
    return r;
}

template<int N> struct PT { float v[N]; };
template<int N>
__host__ __device__ constexpr PT<N> mk_pows(float a) {
    PT<N> t{}; float p = 1.0f;
    for (int i = 0; i < N; ++i) { t.v[i] = p; p *= a; }
    return t;
}

__device__ __forceinline__ v2f shfl_up2(v2f v, int d) {
    v2f r; r.x = __shfl_up(v.x, d, 64); r.y = __shfl_up(v.y, d, 64); return r;
}
__device__ __forceinline__ v2f shfl_down2(v2f v, int d) {
    v2f r; r.x = __shfl_down(v.x, d, 64); r.y = __shfl_down(v.y, d, 64); return r;
}

// scale constants
#define S0 0.015f
#define S1 0.02f
#define S2 0.04f
#define S3 0.08f

__global__ __launch_bounds__(256, 8)
void pcen_kernel(const float* __restrict__ x,
                 const float* __restrict__ log_alpha,
                 const float* __restrict__ log_delta,
                 const float* __restrict__ log_r,
                 const float* __restrict__ z_ks,
                 float* __restrict__ out)
{
#pragma clang fp contract(fast)
    const int tid  = threadIdx.x;
    const int lane = tid & 63;
    const int wid  = tid >> 6;
    const int rid  = blockIdx.x;
    const int f    = rid & (F_DIM - 1);

    __shared__ v2f sE0f[4], sE1f[4];   // forward-scan wave aggregates
    __shared__ v2f sE0b[4], sE1b[4];   // backward-scan wave aggregates

    // ---- issue this thread's 16 global loads FIRST (hide HBM latency under prologue) ----
    const size_t base = (size_t)rid * T_DIM + (size_t)tid * CHUNK;
    const float4* xp = (const float4*)(x + base);
    float4 xq0 = xp[0], xq1 = xp[1], xq2 = xp[2], xq3 = xp[3];

    // ---- softmax denominator over ALL K*F = 1024 z entries, per-wave (no barrier) ----
    float zs = 0.0f;
    #pragma unroll
    for (int j = 0; j < 16; ++j) zs += fexp(z_ks[lane + 64 * j]);
    #pragma unroll
    for (int d = 1; d < 64; d <<= 1) zs += __shfl_xor(zs, d, 64);
    const float invsum = 1.0f / zs;

    float wk[4];
    #pragma unroll
    for (int k = 0; k < 4; ++k) wk[k] = fexp(z_ks[k * F_DIM + f]) * invsum;
    const float alpha = fexp(log_alpha[f]);
    const float delta = fexp(log_delta[f]);
    const float rr    = fexp(log_r[f]);
    const float dr    = fexp2(rr * flog2(delta));   // delta^r (delta > 0)
    const float nalpha = -alpha;

    float xv[CHUNK];
    xv[0]=xq0.x; xv[1]=xq0.y; xv[2]=xq0.z; xv[3]=xq0.w;
    xv[4]=xq1.x; xv[5]=xq1.y; xv[6]=xq1.z; xv[7]=xq1.w;
    xv[8]=xq2.x; xv[9]=xq2.y; xv[10]=xq2.z; xv[11]=xq2.w;
    xv[12]=xq3.x; xv[13]=xq3.y; xv[14]=xq3.z; xv[15]=xq3.w;

    // ---- compile-time coefficient tables for all 4 scales (pairs {0,1} and {2,3}) ----
    constexpr float a0 = 1.0f - S0, a1 = 1.0f - S1, a2 = 1.0f - S2, a3 = 1.0f - S3;
    constexpr float A0 = cpow(a0, CHUNK), A1 = cpow(a1, CHUNK);
    constexpr float A2 = cpow(a2, CHUNK), A3 = cpow(a3, CHUNK);
    constexpr float A64_0 = cpow(a0, 64*CHUNK), A64_1 = cpow(a1, 64*CHUNK);
    constexpr float A64_2 = cpow(a2, 64*CHUNK), A64_3 = cpow(a3, 64*CHUNK);
    constexpr PT<CHUNK+1> P0 = mk_pows<CHUNK+1>(a0);
    constexpr PT<CHUNK+1> P1 = mk_pows<CHUNK+1>(a1);
    constexpr PT<CHUNK+1> P2 = mk_pows<CHUNK+1>(a2);
    constexpr PT<CHUNK+1> P3 = mk_pows<CHUNK+1>(a3);
    constexpr PT<33> PA0 = mk_pows<33>(A0);
    constexpr PT<33> PA1 = mk_pows<33>(A1);
    constexpr PT<33> PA2 = mk_pows<33>(A2);
    constexpr PT<33> PA3 = mk_pows<33>(A3);

    const v2f av01 = {a0, a1}, av23 = {a2, a3};
    const v2f sv01 = {S0, S1}, sv23 = {S2, S3};
    const v2f A64v01 = {A64_0, A64_1}, A64v23 = {A64_2, A64_3};
    const float lgA0 = flog2(A0), lgA1 = flog2(A1), lgA2 = flog2(A2), lgA3 = flog2(A3);
    const v2f zero = {0.0f, 0.0f};

    v2f y0[CHUNK], y1[CHUNK];   // pair {s0,s1} and pair {s2,s3}

    // ===== forward: y[n] = a*y[n-1] + s*x[n], y[0] = x[0] =====
    {
        v2f x0v = {xv[0], xv[0]};
        y0[0] = (tid == 0) ? x0v : (sv01 * x0v);
        y1[0] = (tid == 0) ? x0v : (sv23 * x0v);
    }
    #pragma unroll
    for (int i = 1; i < CHUNK; ++i) {
        v2f xi = {xv[i], xv[i]};
        y0[i] = av01 * y0[i-1] + sv01 * xi;
        y1[i] = av23 * y1[i-1] + sv23 * xi;
    }
    {
        // wave-level inclusive scan of chunk carries (both pairs interleaved)
        v2f e0 = y0[CHUNK-1], e1 = y1[CHUNK-1];
        #pragma unroll
        for (int st = 0; st < 6; ++st) {
            const int d = 1 << st;
            const v2f Ad01 = {PA0.v[d], PA1.v[d]};
            const v2f Ad23 = {PA2.v[d], PA3.v[d]};
            v2f t0 = shfl_up2(e0, d);
            v2f t1 = shfl_up2(e1, d);
            if (lane >= d) { e0 = Ad01 * t0 + e0; e1 = Ad23 * t1 + e1; }
        }
        if (lane == 63) { sE0f[wid] = e0; sE1f[wid] = e1; }
        __syncthreads();
        v2f C0 = zero, C1 = zero;
        for (int j = 0; j < wid; ++j) {
            C0 = A64v01 * C0 + sE0f[j];
            C1 = A64v23 * C1 + sE1f[j];
        }
        v2f ex0 = shfl_up2(e0, 1), ex1 = shfl_up2(e1, 1);
        v2f cp0 = (lane == 0) ? zero : ex0;
        v2f cp1 = (lane == 0) ? zero : ex1;
        const float fl = (float)lane;
        v2f pAl01 = {fexp2(fl * lgA0), fexp2(fl * lgA1)};
        v2f pAl23 = {fexp2(fl * lgA2), fexp2(fl * lgA3)};
        v2f c0 = cp0 + pAl01 * C0;
        v2f c1 = cp1 + pAl23 * C1;
        #pragma unroll
        for (int i = 0; i < CHUNK; ++i) {
            const v2f ap01 = {P0.v[i+1], P1.v[i+1]};
            const v2f ap23 = {P2.v[i+1], P3.v[i+1]};
            y0[i] = ap01 * c0 + y0[i];
            y1[i] = ap23 * c1 + y1[i];
        }
    }

    // ===== backward (in place): z[n] = a*z[n+1] + s*y[n], z[T-1] = y[T-1] =====
    y0[CHUNK-1] = (tid == 255) ? y0[CHUNK-1] : (sv01 * y0[CHUNK-1]);
    y1[CHUNK-1] = (tid == 255) ? y1[CHUNK-1] : (sv23 * y1[CHUNK-1]);
    #pragma unroll
    for (int i = CHUNK-2; i >= 0; --i) {
        y0[i] = av01 * y0[i+1] + sv01 * y0[i];
        y1[i] = av23 * y1[i+1] + sv23 * y1[i];
    }
    {
        v2f e0 = y0[0], e1 = y1[0];
        #pragma unroll
        for (int st = 0; st < 6; ++st) {
            const int d = 1 << st;
            const v2f Ad01 = {PA0.v[d], PA1.v[d]};
            const v2f Ad23 = {PA2.v[d], PA3.v[d]};
            v2f t0 = shfl_down2(e0, d);
            v2f t1 = shfl_down2(e1, d);
            if (lane < 64 - d) { e0 = Ad01 * t0 + e0; e1 = Ad23 * t1 + e1; }
        }
        if (lane == 0) { sE0b[wid] = e0; sE1b[wid] = e1; }   // distinct buffers: no guard barrier
        __syncthreads();
        v2f C0 = zero, C1 = zero;
        for (int j = 3; j > wid; --j) {
            C0 = A64v01 * C0 + sE0b[j];
            C1 = A64v23 * C1 + sE1b[j];
        }
        v2f ex0 = shfl_down2(e0, 1), ex1 = shfl_down2(e1, 1);
        v2f cn0 = (lane == 63) ? zero : ex0;
        v2f cn1 = (lane == 63) ? zero : ex1;
        const float frl = (float)(63 - lane);
        v2f pAr01 = {fexp2(frl * lgA0), fexp2(frl * lgA1)};
        v2f pAr23 = {fexp2(frl * lgA2), fexp2(frl * lgA3)};
        v2f c0 = cn0 + pAr01 * C0;
        v2f c1 = cn1 + pAr23 * C1;
        #pragma unroll
        for (int i = CHUNK-1; i >= 0; --i) {
            const v2f ap01 = {P0.v[CHUNK-i], P1.v[CHUNK-i]};
            const v2f ap23 = {P2.v[CHUNK-i], P3.v[CHUNK-i]};
            y0[i] = ap01 * c0 + y0[i];
            y1[i] = ap23 * c1 + y1[i];
        }
    }

    // ---- epilogue: M = Σ w_k y_k; M' = (M+eps)^(-alpha); out = (x*M'+delta)^r - delta^r ----
    float4* op = (float4*)(out + base);
    const v2f wv01 = {wk[0], wk[1]}, wv23 = {wk[2], wk[3]};
    #pragma unroll
    for (int j = 0; j < 4; ++j) {
        float o[4];
        #pragma unroll
        for (int q = 0; q < 4; ++q) {
            const int i = 4*j + q;
            v2f mp = wv01 * y0[i] + wv23 * y1[i];
            const float M  = mp.x + mp.y;
            const float Mp = fexp2(nalpha * flog2(M + 1.0e-6f));
            const float v  = fmaf(xv[i], Mp, delta);
            o[q] = fexp2(rr * flog2(v)) - dr;
        }
        op[j] = make_float4(o[0], o[1], o[2], o[3]);
    }
}

extern "C" void kernel_launch(void* const* d_in, const int* in_sizes, int n_in,
                              void* d_out, int out_size, void* d_ws, size_t ws_size,
                              hipStream_t stream) {
    const float* x  = (const float*)d_in[0];
    const float* la = (const float*)d_in[1];
    const float* ld = (const float*)d_in[2];
    const float* lr = (const float*)d_in[3];
    const float* zk = (const float*)d_in[4];
    float* o = (float*)d_out;
    (void)in_sizes; (void)n_in; (void)out_size; (void)d_ws; (void)ws_size;
    hipLaunchKernelGGL(pcen_kernel, dim3(NROWS), dim3(256), 0, stream,
                       x, la, ld, lr, zk, o);
}

// Round 6
// 39.484 us; speedup vs baseline: 3.2255x; 3.2255x over previous
//
#include <hip/hip_runtime.h>
#include <math.h>

#define T_DIM 4096
#define F_DIM 256
#define NROWS 4096          // B*C*F = 16*1*256
#define CHUNK 16            // elements per thread; 256 threads * 16 = 4096 = T
#define LOG2E 1.4426950408889634f

typedef float v2f __attribute__((ext_vector_type(2)));

__device__ __forceinline__ float fexp2(float v) { return __builtin_amdgcn_exp2f(v); }
__device__ __forceinline__ float flog2(float v) { return __builtin_amdgcn_logf(v); }
__device__ __forceinline__ float fexp(float v)  { return fexp2(v * LOG2E); }

__host__ __device__ constexpr float cpow(float b, int e) {
    float r = 1.0f;
    for (int i = 0; i < e; ++i) r *= b;
    return r;
}

template<int N> struct PT { float v[N]; };
template<int N>
__host__ __device__ constexpr PT<N> mk_pows(float a) {
    PT<N> t{}; float p = 1.0f;
    for (int i = 0; i < N; ++i) { t.v[i] = p; p *= a; }
    return t;
}

__device__ __forceinline__ v2f shfl_up2(v2f v, int d) {
    v2f r; r.x = __shfl_up(v.x, d, 64); r.y = __shfl_up(v.y, d, 64); return r;
}
__device__ __forceinline__ v2f shfl_down2(v2f v, int d) {
    v2f r; r.x = __shfl_down(v.x, d, 64); r.y = __shfl_down(v.y, d, 64); return r;
}

// scale constants
#define S0 0.015f
#define S1 0.02f
#define S2 0.04f
#define S3 0.08f

__global__ __launch_bounds__(256, 4)
void pcen_kernel(const float* __restrict__ x,
                 const float* __restrict__ log_alpha,
                 const float* __restrict__ log_delta,
                 const float* __restrict__ log_r,
                 const float* __restrict__ z_ks,
                 float* __restrict__ out)
{
#pragma clang fp contract(fast)
    const int tid  = threadIdx.x;
    const int lane = tid & 63;
    const int wid  = tid >> 6;
    const int rid  = blockIdx.x;
    const int f    = rid & (F_DIM - 1);

    __shared__ v2f sE0f[4], sE1f[4];   // forward-scan wave aggregates
    __shared__ v2f sE0b[4], sE1b[4];   // backward-scan wave aggregates

    // ---- issue this thread's 16 global loads FIRST (hide HBM latency under prologue) ----
    const size_t base = (size_t)rid * T_DIM + (size_t)tid * CHUNK;
    const float4* xp = (const float4*)(x + base);
    float4 xq0 = xp[0], xq1 = xp[1], xq2 = xp[2], xq3 = xp[3];

    // ---- per-f parameter loads issued early too ----
    const float v_la = log_alpha[f];
    const float v_ld = log_delta[f];
    const float v_lr = log_r[f];
    float zf[4];
    #pragma unroll
    for (int k = 0; k < 4; ++k) zf[k] = z_ks[k * F_DIM + f];

    // ---- softmax denominator over ALL K*F = 1024 z entries, per-wave (no barrier) ----
    float zs = 0.0f;
    #pragma unroll
    for (int j = 0; j < 16; ++j) zs += fexp(z_ks[lane + 64 * j]);
    #pragma unroll
    for (int d = 1; d < 64; d <<= 1) zs += __shfl_xor(zs, d, 64);
    const float invsum = 1.0f / zs;

    float wk[4];
    #pragma unroll
    for (int k = 0; k < 4; ++k) wk[k] = fexp(zf[k]) * invsum;
    const float alpha = fexp(v_la);
    const float delta = fexp(v_ld);
    const float rr    = fexp(v_lr);
    const float dr    = fexp2(rr * flog2(delta));   // delta^r (delta > 0)
    const float nalpha = -alpha;

    float xv[CHUNK];
    xv[0]=xq0.x; xv[1]=xq0.y; xv[2]=xq0.z; xv[3]=xq0.w;
    xv[4]=xq1.x; xv[5]=xq1.y; xv[6]=xq1.z; xv[7]=xq1.w;
    xv[8]=xq2.x; xv[9]=xq2.y; xv[10]=xq2.z; xv[11]=xq2.w;
    xv[12]=xq3.x; xv[13]=xq3.y; xv[14]=xq3.z; xv[15]=xq3.w;

    // ---- compile-time coefficient tables for all 4 scales (pairs {0,1} and {2,3}) ----
    constexpr float a0 = 1.0f - S0, a1 = 1.0f - S1, a2 = 1.0f - S2, a3 = 1.0f - S3;
    constexpr float A0 = cpow(a0, CHUNK), A1 = cpow(a1, CHUNK);
    constexpr float A2 = cpow(a2, CHUNK), A3 = cpow(a3, CHUNK);
    constexpr float A64_0 = cpow(a0, 64*CHUNK), A64_1 = cpow(a1, 64*CHUNK);
    constexpr float A64_2 = cpow(a2, 64*CHUNK), A64_3 = cpow(a3, 64*CHUNK);
    constexpr PT<CHUNK+1> P0 = mk_pows<CHUNK+1>(a0);
    constexpr PT<CHUNK+1> P1 = mk_pows<CHUNK+1>(a1);
    constexpr PT<CHUNK+1> P2 = mk_pows<CHUNK+1>(a2);
    constexpr PT<CHUNK+1> P3 = mk_pows<CHUNK+1>(a3);
    constexpr PT<33> PA0 = mk_pows<33>(A0);
    constexpr PT<33> PA1 = mk_pows<33>(A1);
    constexpr PT<33> PA2 = mk_pows<33>(A2);
    constexpr PT<33> PA3 = mk_pows<33>(A3);

    const v2f av01 = {a0, a1}, av23 = {a2, a3};
    const v2f sv01 = {S0, S1}, sv23 = {S2, S3};
    const v2f A64v01 = {A64_0, A64_1}, A64v23 = {A64_2, A64_3};
    const float lgA0 = flog2(A0), lgA1 = flog2(A1), lgA2 = flog2(A2), lgA3 = flog2(A3);
    const v2f zero = {0.0f, 0.0f};

    v2f y0[CHUNK], y1[CHUNK];   // pair {s0,s1} and pair {s2,s3}

    // ===== forward: y[n] = a*y[n-1] + s*x[n], y[0] = x[0] =====
    {
        v2f x0v = {xv[0], xv[0]};
        y0[0] = (tid == 0) ? x0v : (sv01 * x0v);
        y1[0] = (tid == 0) ? x0v : (sv23 * x0v);
    }
    #pragma unroll
    for (int i = 1; i < CHUNK; ++i) {
        v2f xi = {xv[i], xv[i]};
        y0[i] = av01 * y0[i-1] + sv01 * xi;
        y1[i] = av23 * y1[i-1] + sv23 * xi;
    }
    {
        // wave-level inclusive scan of chunk carries (both pairs interleaved)
        v2f e0 = y0[CHUNK-1], e1 = y1[CHUNK-1];
        #pragma unroll
        for (int st = 0; st < 6; ++st) {
            const int d = 1 << st;
            const v2f Ad01 = {PA0.v[d], PA1.v[d]};
            const v2f Ad23 = {PA2.v[d], PA3.v[d]};
            v2f t0 = shfl_up2(e0, d);
            v2f t1 = shfl_up2(e1, d);
            if (lane >= d) { e0 = Ad01 * t0 + e0; e1 = Ad23 * t1 + e1; }
        }
        if (lane == 63) { sE0f[wid] = e0; sE1f[wid] = e1; }
        __syncthreads();
        v2f C0 = zero, C1 = zero;
        for (int j = 0; j < wid; ++j) {
            C0 = A64v01 * C0 + sE0f[j];
            C1 = A64v23 * C1 + sE1f[j];
        }
        v2f ex0 = shfl_up2(e0, 1), ex1 = shfl_up2(e1, 1);
        v2f cp0 = (lane == 0) ? zero : ex0;
        v2f cp1 = (lane == 0) ? zero : ex1;
        const float fl = (float)lane;
        v2f pAl01 = {fexp2(fl * lgA0), fexp2(fl * lgA1)};
        v2f pAl23 = {fexp2(fl * lgA2), fexp2(fl * lgA3)};
        v2f c0 = cp0 + pAl01 * C0;
        v2f c1 = cp1 + pAl23 * C1;
        #pragma unroll
        for (int i = 0; i < CHUNK; ++i) {
            const v2f ap01 = {P0.v[i+1], P1.v[i+1]};
            const v2f ap23 = {P2.v[i+1], P3.v[i+1]};
            y0[i] = ap01 * c0 + y0[i];
            y1[i] = ap23 * c1 + y1[i];
        }
    }

    // ===== backward (in place): z[n] = a*z[n+1] + s*y[n], z[T-1] = y[T-1] =====
    y0[CHUNK-1] = (tid == 255) ? y0[CHUNK-1] : (sv01 * y0[CHUNK-1]);
    y1[CHUNK-1] = (tid == 255) ? y1[CHUNK-1] : (sv23 * y1[CHUNK-1]);
    #pragma unroll
    for (int i = CHUNK-2; i >= 0; --i) {
        y0[i] = av01 * y0[i+1] + sv01 * y0[i];
        y1[i] = av23 * y1[i+1] + sv23 * y1[i];
    }
    {
        v2f e0 = y0[0], e1 = y1[0];
        #pragma unroll
        for (int st = 0; st < 6; ++st) {
            const int d = 1 << st;
            const v2f Ad01 = {PA0.v[d], PA1.v[d]};
            const v2f Ad23 = {PA2.v[d], PA3.v[d]};
            v2f t0 = shfl_down2(e0, d);
            v2f t1 = shfl_down2(e1, d);
            if (lane < 64 - d) { e0 = Ad01 * t0 + e0; e1 = Ad23 * t1 + e1; }
        }
        if (lane == 0) { sE0b[wid] = e0; sE1b[wid] = e1; }   // distinct buffers: no guard barrier
        __syncthreads();
        v2f C0 = zero, C1 = zero;
        for (int j = 3; j > wid; --j) {
            C0 = A64v01 * C0 + sE0b[j];
            C1 = A64v23 * C1 + sE1b[j];
        }
        v2f ex0 = shfl_down2(e0, 1), ex1 = shfl_down2(e1, 1);
        v2f cn0 = (lane == 63) ? zero : ex0;
        v2f cn1 = (lane == 63) ? zero : ex1;
        const float frl = (float)(63 - lane);
        v2f pAr01 = {fexp2(frl * lgA0), fexp2(frl * lgA1)};
        v2f pAr23 = {fexp2(frl * lgA2), fexp2(frl * lgA3)};
        v2f c0 = cn0 + pAr01 * C0;
        v2f c1 = cn1 + pAr23 * C1;
        #pragma unroll
        for (int i = CHUNK-1; i >= 0; --i) {
            const v2f ap01 = {P0.v[CHUNK-i], P1.v[CHUNK-i]};
            const v2f ap23 = {P2.v[CHUNK-i], P3.v[CHUNK-i]};
            y0[i] = ap01 * c0 + y0[i];
            y1[i] = ap23 * c1 + y1[i];
        }
    }

    // ---- epilogue: M = Σ w_k y_k; M' = (M+eps)^(-alpha); out = (x*M'+delta)^r - delta^r ----
    float4* op = (float4*)(out + base);
    const v2f wv01 = {wk[0], wk[1]}, wv23 = {wk[2], wk[3]};
    #pragma unroll
    for (int j = 0; j < 4; ++j) {
        float o[4];
        #pragma unroll
        for (int q = 0; q < 4; ++q) {
            const int i = 4*j + q;
            v2f mp = wv01 * y0[i] + wv23 * y1[i];
            const float M  = mp.x + mp.y;
            const float Mp = fexp2(nalpha * flog2(M + 1.0e-6f));
            const float v  = fmaf(xv[i], Mp, delta);
            o[q] = fexp2(rr * flog2(v)) - dr;
        }
        op[j] = make_float4(o[0], o[1], o[2], o[3]);
    }
}

extern "C" void kernel_launch(void* const* d_in, const int* in_sizes, int n_in,
                              void* d_out, int out_size, void* d_ws, size_t ws_size,
                              hipStream_t stream) {
    const float* x  = (const float*)d_in[0];
    const float* la = (const float*)d_in[1];
    const float* ld = (const float*)d_in[2];
    const float* lr = (const float*)d_in[3];
    const float* zk = (const float*)d_in[4];
    float* o = (float*)d_out;
    (void)in_sizes; (void)n_in; (void)out_size; (void)d_ws; (void)ws_size;
    hipLaunchKernelGGL(pcen_kernel, dim3(NROWS), dim3(256), 0, stream,
                       x, la, ld, lr, zk, o);
}

// Round 7
// 39.184 us; speedup vs baseline: 3.2503x; 1.0077x over previous
//
#include <hip/hip_runtime.h>
#include <math.h>

#define T_DIM 4096
#define F_DIM 256
#define NROWS 4096          // B*C*F = 16*1*256
#define CHUNK 16            // elements per thread; 256 threads * 16 = 4096 = T
#define LOG2E 1.4426950408889634f

typedef float v2f __attribute__((ext_vector_type(2)));

__device__ __forceinline__ float fexp2(float v) { return __builtin_amdgcn_exp2f(v); }
__device__ __forceinline__ float flog2(float v) { return __builtin_amdgcn_logf(v); }
__device__ __forceinline__ float fexp(float v)  { return fexp2(v * LOG2E); }

__host__ __device__ constexpr float cpow(float b, int e) {
    float r = 1.0f;
    for (int i = 0; i < e; ++i) r *= b;
    return r;
}

template<int N> struct PT { float v[N]; };
template<int N>
__host__ __device__ constexpr PT<N> mk_pows(float a) {
    PT<N> t{}; float p = 1.0f;
    for (int i = 0; i < N; ++i) { t.v[i] = p; p *= a; }
    return t;
}

__device__ __forceinline__ v2f shfl_up2(v2f v, int d) {
    v2f r; r.x = __shfl_up(v.x, d, 64); r.y = __shfl_up(v.y, d, 64); return r;
}
__device__ __forceinline__ v2f shfl_down2(v2f v, int d) {
    v2f r; r.x = __shfl_down(v.x, d, 64); r.y = __shfl_down(v.y, d, 64); return r;
}

// scale constants
#define S0 0.015f
#define S1 0.02f
#define S2 0.04f
#define S3 0.08f

// ---------- kernel A: per-frequency parameter precompute (1 block, 256 threads) ----------
// ws layout: per f, 8 floats = {wk0, wk1, wk2, wk3, -alpha, delta, rr, delta^r}
__global__ __launch_bounds__(256)
void pcen_params(const float* __restrict__ log_alpha,
                 const float* __restrict__ log_delta,
                 const float* __restrict__ log_r,
                 const float* __restrict__ z_ks,
                 float* __restrict__ ws)
{
    const int f    = threadIdx.x;        // 0..255
    const int lane = f & 63;
    const int wid  = f >> 6;
    __shared__ float sred[4];

    float ez[4];
    #pragma unroll
    for (int k = 0; k < 4; ++k) ez[k] = fexp(z_ks[k * F_DIM + f]);
    float zs = ez[0] + ez[1] + ez[2] + ez[3];
    #pragma unroll
    for (int d = 1; d < 64; d <<= 1) zs += __shfl_xor(zs, d, 64);
    if (lane == 0) sred[wid] = zs;
    __syncthreads();
    const float invsum = 1.0f / (sred[0] + sred[1] + sred[2] + sred[3]);

    const float alpha = fexp(log_alpha[f]);
    const float delta = fexp(log_delta[f]);
    const float rr    = fexp(log_r[f]);
    const float dr    = fexp2(rr * flog2(delta));   // delta^r (delta > 0)

    float4* w4 = (float4*)ws;
    w4[f * 2]     = make_float4(ez[0] * invsum, ez[1] * invsum, ez[2] * invsum, ez[3] * invsum);
    w4[f * 2 + 1] = make_float4(-alpha, delta, rr, dr);
}

// ---------- kernel B: main PCEN ----------
__global__ __launch_bounds__(256, 4)
void pcen_kernel(const float* __restrict__ x,
                 const float* __restrict__ ws,
                 float* __restrict__ out)
{
#pragma clang fp contract(fast)
    const int tid  = threadIdx.x;
    const int lane = tid & 63;
    const int wid  = tid >> 6;
    const int rid  = blockIdx.x;
    const int f    = rid & (F_DIM - 1);

    __shared__ v2f sE0f[4], sE1f[4];   // forward-scan wave aggregates
    __shared__ v2f sE0b[4], sE1b[4];   // backward-scan wave aggregates

    // ---- issue all global loads FIRST (hide HBM latency) ----
    const size_t base = (size_t)rid * T_DIM + (size_t)tid * CHUNK;
    const float4* xp = (const float4*)(x + base);
    float4 xq0 = xp[0], xq1 = xp[1], xq2 = xp[2], xq3 = xp[3];
    const float4* w4 = (const float4*)ws;
    const float4 pw = w4[f * 2];       // wk0..3
    const float4 pp = w4[f * 2 + 1];   // -alpha, delta, rr, dr

    const float nalpha = pp.x;
    const float delta  = pp.y;
    const float rr     = pp.z;
    const float dr     = pp.w;

    float xv[CHUNK];
    xv[0]=xq0.x; xv[1]=xq0.y; xv[2]=xq0.z; xv[3]=xq0.w;
    xv[4]=xq1.x; xv[5]=xq1.y; xv[6]=xq1.z; xv[7]=xq1.w;
    xv[8]=xq2.x; xv[9]=xq2.y; xv[10]=xq2.z; xv[11]=xq2.w;
    xv[12]=xq3.x; xv[13]=xq3.y; xv[14]=xq3.z; xv[15]=xq3.w;

    // ---- compile-time coefficient tables for all 4 scales (pairs {0,1} and {2,3}) ----
    constexpr float a0 = 1.0f - S0, a1 = 1.0f - S1, a2 = 1.0f - S2, a3 = 1.0f - S3;
    constexpr float A0 = cpow(a0, CHUNK), A1 = cpow(a1, CHUNK);
    constexpr float A2 = cpow(a2, CHUNK), A3 = cpow(a3, CHUNK);
    constexpr float A64_0 = cpow(a0, 64*CHUNK), A64_1 = cpow(a1, 64*CHUNK);
    constexpr float A64_2 = cpow(a2, 64*CHUNK), A64_3 = cpow(a3, 64*CHUNK);
    constexpr PT<CHUNK+1> P0 = mk_pows<CHUNK+1>(a0);
    constexpr PT<CHUNK+1> P1 = mk_pows<CHUNK+1>(a1);
    constexpr PT<CHUNK+1> P2 = mk_pows<CHUNK+1>(a2);
    constexpr PT<CHUNK+1> P3 = mk_pows<CHUNK+1>(a3);
    constexpr PT<33> PA0 = mk_pows<33>(A0);
    constexpr PT<33> PA1 = mk_pows<33>(A1);
    constexpr PT<33> PA2 = mk_pows<33>(A2);
    constexpr PT<33> PA3 = mk_pows<33>(A3);

    const v2f av01 = {a0, a1}, av23 = {a2, a3};
    const v2f sv01 = {S0, S1}, sv23 = {S2, S3};
    const v2f A64v01 = {A64_0, A64_1}, A64v23 = {A64_2, A64_3};
    const float lgA0 = flog2(A0), lgA1 = flog2(A1), lgA2 = flog2(A2), lgA3 = flog2(A3);
    const v2f zero = {0.0f, 0.0f};

    v2f y0[CHUNK], y1[CHUNK];   // pair {s0,s1} and pair {s2,s3}

    // ===== forward: y[n] = a*y[n-1] + s*x[n], y[0] = x[0] =====
    {
        v2f x0v = {xv[0], xv[0]};
        y0[0] = (tid == 0) ? x0v : (sv01 * x0v);
        y1[0] = (tid == 0) ? x0v : (sv23 * x0v);
    }
    #pragma unroll
    for (int i = 1; i < CHUNK; ++i) {
        v2f xi = {xv[i], xv[i]};
        y0[i] = av01 * y0[i-1] + sv01 * xi;
        y1[i] = av23 * y1[i-1] + sv23 * xi;
    }
    {
        // wave-level inclusive scan of chunk carries (both pairs interleaved)
        v2f e0 = y0[CHUNK-1], e1 = y1[CHUNK-1];
        #pragma unroll
        for (int st = 0; st < 6; ++st) {
            const int d = 1 << st;
            const v2f Ad01 = {PA0.v[d], PA1.v[d]};
            const v2f Ad23 = {PA2.v[d], PA3.v[d]};
            v2f t0 = shfl_up2(e0, d);
            v2f t1 = shfl_up2(e1, d);
            if (lane >= d) { e0 = Ad01 * t0 + e0; e1 = Ad23 * t1 + e1; }
        }
        if (lane == 63) { sE0f[wid] = e0; sE1f[wid] = e1; }
        __syncthreads();
        v2f C0 = zero, C1 = zero;
        for (int j = 0; j < wid; ++j) {
            C0 = A64v01 * C0 + sE0f[j];
            C1 = A64v23 * C1 + sE1f[j];
        }
        v2f ex0 = shfl_up2(e0, 1), ex1 = shfl_up2(e1, 1);
        v2f cp0 = (lane == 0) ? zero : ex0;
        v2f cp1 = (lane == 0) ? zero : ex1;
        const float fl = (float)lane;
        v2f pAl01 = {fexp2(fl * lgA0), fexp2(fl * lgA1)};
        v2f pAl23 = {fexp2(fl * lgA2), fexp2(fl * lgA3)};
        v2f c0 = cp0 + pAl01 * C0;
        v2f c1 = cp1 + pAl23 * C1;
        #pragma unroll
        for (int i = 0; i < CHUNK; ++i) {
            const v2f ap01 = {P0.v[i+1], P1.v[i+1]};
            const v2f ap23 = {P2.v[i+1], P3.v[i+1]};
            y0[i] = ap01 * c0 + y0[i];
            y1[i] = ap23 * c1 + y1[i];
        }
    }

    // ===== backward (in place): z[n] = a*z[n+1] + s*y[n], z[T-1] = y[T-1] =====
    y0[CHUNK-1] = (tid == 255) ? y0[CHUNK-1] : (sv01 * y0[CHUNK-1]);
    y1[CHUNK-1] = (tid == 255) ? y1[CHUNK-1] : (sv23 * y1[CHUNK-1]);
    #pragma unroll
    for (int i = CHUNK-2; i >= 0; --i) {
        y0[i] = av01 * y0[i+1] + sv01 * y0[i];
        y1[i] = av23 * y1[i+1] + sv23 * y1[i];
    }
    {
        v2f e0 = y0[0], e1 = y1[0];
        #pragma unroll
        for (int st = 0; st < 6; ++st) {
            const int d = 1 << st;
            const v2f Ad01 = {PA0.v[d], PA1.v[d]};
            const v2f Ad23 = {PA2.v[d], PA3.v[d]};
            v2f t0 = shfl_down2(e0, d);
            v2f t1 = shfl_down2(e1, d);
            if (lane < 64 - d) { e0 = Ad01 * t0 + e0; e1 = Ad23 * t1 + e1; }
        }
        if (lane == 0) { sE0b[wid] = e0; sE1b[wid] = e1; }   // distinct buffers: no guard barrier
        __syncthreads();
        v2f C0 = zero, C1 = zero;
        for (int j = 3; j > wid; --j) {
            C0 = A64v01 * C0 + sE0b[j];
            C1 = A64v23 * C1 + sE1b[j];
        }
        v2f ex0 = shfl_down2(e0, 1), ex1 = shfl_down2(e1, 1);
        v2f cn0 = (lane == 63) ? zero : ex0;
        v2f cn1 = (lane == 63) ? zero : ex1;
        const float frl = (float)(63 - lane);
        v2f pAr01 = {fexp2(frl * lgA0), fexp2(frl * lgA1)};
        v2f pAr23 = {fexp2(frl * lgA2), fexp2(frl * lgA3)};
        v2f c0 = cn0 + pAr01 * C0;
        v2f c1 = cn1 + pAr23 * C1;
        #pragma unroll
        for (int i = CHUNK-1; i >= 0; --i) {
            const v2f ap01 = {P0.v[CHUNK-i], P1.v[CHUNK-i]};
            const v2f ap23 = {P2.v[CHUNK-i], P3.v[CHUNK-i]};
            y0[i] = ap01 * c0 + y0[i];
            y1[i] = ap23 * c1 + y1[i];
        }
    }

    // ---- epilogue: M = Σ w_k y_k; M' = (M+eps)^(-alpha); out = (x*M'+delta)^r - delta^r ----
    float4* op = (float4*)(out + base);
    const v2f wv01 = {pw.x, pw.y}, wv23 = {pw.z, pw.w};
    #pragma unroll
    for (int j = 0; j < 4; ++j) {
        float o[4];
        #pragma unroll
        for (int q = 0; q < 4; ++q) {
            const int i = 4*j + q;
            v2f mp = wv01 * y0[i] + wv23 * y1[i];
            const float M  = mp.x + mp.y;
            const float Mp = fexp2(nalpha * flog2(M + 1.0e-6f));
            const float v  = fmaf(xv[i], Mp, delta);
            o[q] = fexp2(rr * flog2(v)) - dr;
        }
        op[j] = make_float4(o[0], o[1], o[2], o[3]);
    }
}

extern "C" void kernel_launch(void* const* d_in, const int* in_sizes, int n_in,
                              void* d_out, int out_size, void* d_ws, size_t ws_size,
                              hipStream_t stream) {
    const float* x  = (const float*)d_in[0];
    const float* la = (const float*)d_in[1];
    const float* ld = (const float*)d_in[2];
    const float* lr = (const float*)d_in[3];
    const float* zk = (const float*)d_in[4];
    float* o  = (float*)d_out;
    float* ws = (float*)d_ws;    // needs 256*8*4 = 8 KB
    (void)in_sizes; (void)n_in; (void)out_size; (void)ws_size;
    hipLaunchKernelGGL(pcen_params, dim3(1), dim3(256), 0, stream, la, ld, lr, zk, ws);
    hipLaunchKernelGGL(pcen_kernel, dim3(NROWS), dim3(256), 0, stream, x, ws, o);
}